// Round 1
// baseline (498.279 us; speedup 1.0000x reference)
//
#include <hip/hip_runtime.h>
#include <stdint.h>

typedef unsigned long long u64;
typedef unsigned int u32;

#define NB 32     // batches
#define NP 8192   // points per batch
#define NG 256    // FPS centers
#define NK 32     // neighbors per center

// Exact IEEE ops (block FMA contraction so we bit-match the numpy reference):
// d = ((dx*dx) + (dy*dy)) + (dz*dz)
__device__ __forceinline__ float dist3(float dx, float dy, float dz) {
    return __fadd_rn(__fadd_rn(__fmul_rn(dx, dx), __fmul_rn(dy, dy)), __fmul_rn(dz, dz));
}

__device__ __forceinline__ u64 shfl_xor_u64(u64 v, int mask) {
    u32 lo = (u32)(v & 0xFFFFFFFFull);
    u32 hi = (u32)(v >> 32);
    lo = (u32)__shfl_xor((int)lo, mask, 64);
    hi = (u32)__shfl_xor((int)hi, mask, 64);
    return ((u64)hi << 32) | (u64)lo;
}

// ---------------------------------------------------------------------------
// Kernel 1: farthest point sampling. One block per batch, 1024 threads,
// 8 points per thread fully register-resident. Writes centers to
// out[(b*NG+g)*3 + c]. Bit-exact replication of the reference iteration:
//   dist = min(dist, ||p - centroid||^2);  farthest = argmax(dist) (first max)
// Output slot g+1 gets the winner of iteration g; slot 0 is point 0.
// ---------------------------------------------------------------------------
__global__ __launch_bounds__(1024) void fps_kernel(const float* __restrict__ xyz,
                                                   float* __restrict__ out)
{
    const int b = blockIdx.x;
    const int t = threadIdx.x;
    const int p0 = t * 8;

    __shared__ u64 wavemax[16];
    __shared__ float cx_s, cy_s, cz_s;

    float px[8], py[8], pz[8], dist[8];
    {
        const float4* src = reinterpret_cast<const float4*>(xyz + (size_t)b * NP * 3 + (size_t)p0 * 3);
        float4 f0 = src[0], f1 = src[1], f2 = src[2], f3 = src[3], f4 = src[4], f5 = src[5];
        float a[24] = {f0.x,f0.y,f0.z,f0.w, f1.x,f1.y,f1.z,f1.w, f2.x,f2.y,f2.z,f2.w,
                       f3.x,f3.y,f3.z,f3.w, f4.x,f4.y,f4.z,f4.w, f5.x,f5.y,f5.z,f5.w};
        #pragma unroll
        for (int j = 0; j < 8; ++j) {
            px[j] = a[3*j]; py[j] = a[3*j+1]; pz[j] = a[3*j+2];
            dist[j] = 1e10f;
        }
    }

    if (t == 0) {
        cx_s = px[0]; cy_s = py[0]; cz_s = pz[0];
        float* c0 = out + (size_t)b * NG * 3;
        c0[0] = px[0]; c0[1] = py[0]; c0[2] = pz[0];
    }
    __syncthreads();

    const int wid = t >> 6;
    for (int g = 0; g < NG; ++g) {
        const float cx = cx_s, cy = cy_s, cz = cz_s;
        u64 best = 0;
        #pragma unroll
        for (int j = 0; j < 8; ++j) {
            float dx = __fsub_rn(px[j], cx);
            float dy = __fsub_rn(py[j], cy);
            float dz = __fsub_rn(pz[j], cz);
            float d  = dist3(dx, dy, dz);
            float dm = fminf(dist[j], d);
            dist[j] = dm;
            // argmax with first-index tie-break: bigger dist wins; equal dist ->
            // bigger (NP-1-idx) = smaller idx wins. dist >= 0 so bits are monotone.
            u64 k = ((u64)__float_as_uint(dm) << 32) | (u64)(u32)(NP - 1 - (p0 + j));
            best = (k > best) ? k : best;
        }
        #pragma unroll
        for (int m = 32; m >= 1; m >>= 1) {
            u64 o = shfl_xor_u64(best, m);
            best = (o > best) ? o : best;
        }
        if ((t & 63) == 0) wavemax[wid] = best;
        __syncthreads();

        u64 win = wavemax[0];
        #pragma unroll
        for (int w = 1; w < 16; ++w) {
            u64 o = wavemax[w];
            win = (o > win) ? o : win;
        }
        const int widx = NP - 1 - (int)(u32)(win & 0xFFFFFFFFull);
        if ((widx >> 3) == t) {
            const int j = widx & 7;
            cx_s = px[j]; cy_s = py[j]; cz_s = pz[j];
            if (g < NG - 1) {
                float* c = out + ((size_t)b * NG + (g + 1)) * 3;
                c[0] = px[j]; c[1] = py[j]; c[2] = pz[j];
            }
        }
        __syncthreads();
    }
}

// ---------------------------------------------------------------------------
// Kernel 2: 32-NN mean per (batch, center). One WAVE per task (no LDS, no
// barriers). Each lane streams 128 points, keeps its 4 smallest packed keys
// (key = monotone-mapped f32 dist, reference formula (s2 - 2*dot) + n2);
// 32 rounds of wave-min butterfly extract the global top-32. Lazy exact
// rescan if a lane's 4-entry list empties (P ~ 1% per task).
// ---------------------------------------------------------------------------
__device__ __forceinline__ void build_top4(const float4* __restrict__ src,
                                           float cx, float cy, float cz, float s2,
                                           u64 L, bool useL, int lane,
                                           u64& t0, u64& t1, u64& t2, u64& t3)
{
    t0 = t1 = t2 = t3 = ~0ull;
    for (int q = 0; q < 32; ++q) {
        float4 f0 = src[q*3+0];
        float4 f1 = src[q*3+1];
        float4 f2 = src[q*3+2];
        float a[12] = {f0.x,f0.y,f0.z,f0.w, f1.x,f1.y,f1.z,f1.w, f2.x,f2.y,f2.z,f2.w};
        #pragma unroll
        for (int rr = 0; rr < 4; ++rr) {
            float nx = a[rr*3+0], ny = a[rr*3+1], nz = a[rr*3+2];
            // reference: (||s||^2 - 2*(s.n)) + ||n||^2, left-to-right, no FMA
            float dotv = __fadd_rn(__fadd_rn(__fmul_rn(cx,nx), __fmul_rn(cy,ny)), __fmul_rn(cz,nz));
            float n2   = dist3(nx, ny, nz);
            float d    = __fadd_rn(__fsub_rn(s2, __fmul_rn(2.0f, dotv)), n2);
            // monotone map f32 -> u32 (handles the tiny-negative self-distance case)
            u32 u  = __float_as_uint(d);
            u32 kk = u ^ (u32)(((int)u >> 31) | 0x80000000);
            int idx = lane * 128 + q * 4 + rr;
            u64 pk = ((u64)kk << 32) | (u64)(u32)idx;
            if (!useL || pk > L) {
                if (pk < t3) {
                    t3 = pk;
                    if (t3 < t2) { u64 tmp = t2; t2 = t3; t3 = tmp; }
                    if (t2 < t1) { u64 tmp = t1; t1 = t2; t2 = tmp; }
                    if (t1 < t0) { u64 tmp = t0; t0 = t1; t1 = tmp; }
                }
            }
        }
    }
}

__global__ __launch_bounds__(256) void knn_kernel(const float* __restrict__ xyz,
                                                  float* __restrict__ out)
{
    const int t    = threadIdx.x;
    const int lane = t & 63;
    const int wid  = t >> 6;
    const int task = blockIdx.x * 4 + wid;   // 0..8191
    const int b    = task >> 8;
    const int g    = task & 255;

    const float* cptr = out + ((size_t)b * NG + g) * 3;   // centers written by fps_kernel
    const float cx = cptr[0], cy = cptr[1], cz = cptr[2];
    const float s2 = dist3(cx, cy, cz);

    const float4* src = reinterpret_cast<const float4*>(xyz + (size_t)b * NP * 3) + (size_t)lane * 96;

    u64 t0, t1, t2, t3;
    build_top4(src, cx, cy, cz, s2, 0ull, false, lane, t0, t1, t2, t3);
    int cnt = 4;
    u64 L = 0;
    u32 myWin = 0;

    for (int round = 0; round < NK; ++round) {
        if (cnt == 0) {
            // lane exhausted its 4 candidates: exact refill with keys > last extracted.
            build_top4(src, cx, cy, cz, s2, L, true, lane, t0, t1, t2, t3);
            cnt = 4;
        }
        u64 cand = t0;
        u64 w = cand;
        #pragma unroll
        for (int m = 32; m >= 1; m >>= 1) {
            u64 o = shfl_xor_u64(w, m);
            w = (o < w) ? o : w;
        }
        if (cand == w) {          // unique owner (idx packed in key)
            t0 = t1; t1 = t2; t2 = t3; t3 = ~0ull;
            --cnt;
            L = w;
        }
        if (lane == round) myWin = (u32)(w & 0xFFFFFFFFull);
    }

    float sx = 0.f, sy = 0.f, sz = 0.f;
    if (lane < NK) {
        const float* p = xyz + ((size_t)b * NP + myWin) * 3;
        sx = p[0]; sy = p[1]; sz = p[2];
    }
    #pragma unroll
    for (int m = 32; m >= 1; m >>= 1) {
        sx += __shfl_xor(sx, m, 64);
        sy += __shfl_xor(sy, m, 64);
        sz += __shfl_xor(sz, m, 64);
    }
    if (lane == 0) {
        float* o = out + (size_t)NB * NG * 3 + ((size_t)b * NG + g) * 3;
        const float inv = 1.0f / 32.0f;   // /32 is exact (power of 2)
        o[0] = sx * inv; o[1] = sy * inv; o[2] = sz * inv;
    }
}

extern "C" void kernel_launch(void* const* d_in, const int* in_sizes, int n_in,
                              void* d_out, int out_size, void* d_ws, size_t ws_size,
                              hipStream_t stream)
{
    const float* xyz = (const float*)d_in[0];
    float* out = (float*)d_out;

    hipLaunchKernelGGL(fps_kernel, dim3(NB), dim3(1024), 0, stream, xyz, out);

    const int tasks  = NB * NG;            // 8192
    const int blocks = tasks / 4;          // 4 waves (tasks) per 256-thread block
    hipLaunchKernelGGL(knn_kernel, dim3(blocks), dim3(256), 0, stream, xyz, out);
}

// Round 2
// 369.421 us; speedup vs baseline: 1.3488x; 1.3488x over previous
//
#include <hip/hip_runtime.h>
#include <stdint.h>

typedef unsigned long long u64;
typedef unsigned int u32;

#define NB 32     // batches
#define NP 8192   // points per batch
#define NG 256    // FPS centers
#define NK 32     // neighbors per center

// Exact IEEE ops (block FMA contraction so we bit-match the numpy reference):
// d = ((dx*dx) + (dy*dy)) + (dz*dz)
__device__ __forceinline__ float dist3(float dx, float dy, float dz) {
    return __fadd_rn(__fadd_rn(__fmul_rn(dx, dx), __fmul_rn(dy, dy)), __fmul_rn(dz, dz));
}

// ---- DPP wave reductions (VALU-only, no LDS pipe) ----------------------------
// row_shr:1/2/4/8 accumulate within 16-lane rows (lane15 of each row holds the
// row result), then row_bcast15 (rows 1,3) and row_bcast31 (rows 2,3) combine
// rows; lane 63 holds the full 64-lane result; readlane broadcasts it.
#define DPP_STEP(v, ctrl, rmask) __builtin_amdgcn_update_dpp((int)(v), (int)(v), (ctrl), (rmask), 0xf, false)

__device__ __forceinline__ u32 wave_max_u32(u32 v) {
    u32 o;
    o = (u32)DPP_STEP(v, 0x111, 0xf); v = (o > v) ? o : v;  // row_shr:1
    o = (u32)DPP_STEP(v, 0x112, 0xf); v = (o > v) ? o : v;  // row_shr:2
    o = (u32)DPP_STEP(v, 0x114, 0xf); v = (o > v) ? o : v;  // row_shr:4
    o = (u32)DPP_STEP(v, 0x118, 0xf); v = (o > v) ? o : v;  // row_shr:8
    o = (u32)DPP_STEP(v, 0x142, 0xa); v = (o > v) ? o : v;  // row_bcast:15
    o = (u32)DPP_STEP(v, 0x143, 0xc); v = (o > v) ? o : v;  // row_bcast:31
    return (u32)__builtin_amdgcn_readlane((int)v, 63);
}

__device__ __forceinline__ u32 wave_min_u32(u32 v) {
    u32 o;
    o = (u32)DPP_STEP(v, 0x111, 0xf); v = (o < v) ? o : v;
    o = (u32)DPP_STEP(v, 0x112, 0xf); v = (o < v) ? o : v;
    o = (u32)DPP_STEP(v, 0x114, 0xf); v = (o < v) ? o : v;
    o = (u32)DPP_STEP(v, 0x118, 0xf); v = (o < v) ? o : v;
    o = (u32)DPP_STEP(v, 0x142, 0xa); v = (o < v) ? o : v;
    o = (u32)DPP_STEP(v, 0x143, 0xc); v = (o < v) ? o : v;
    return (u32)__builtin_amdgcn_readlane((int)v, 63);
}

// ---------------------------------------------------------------------------
// Kernel 1: farthest point sampling. One block (512 threads, 8 waves) per
// batch; 16 register-resident points per thread. One barrier per iteration:
// wavekey is parity-double-buffered, and the next centroid is fetched by ALL
// lanes via a same-address global load (L2-hot broadcast) instead of an
// owner-write + second barrier.
// Bit-exact vs reference: dist = min(dist, ((dx*dx)+(dy*dy))+(dz*dz));
// argmax = first index of max (strict > over ascending j; cross-lane and
// cross-wave ties resolved to the larger (NP-1-idx), i.e. the smaller idx).
// ---------------------------------------------------------------------------
__global__ __launch_bounds__(512) void fps_kernel(const float* __restrict__ xyz,
                                                  float* __restrict__ out)
{
    const int b = blockIdx.x;
    const int t = threadIdx.x;
    const int wid = t >> 6, lane = t & 63;

    __shared__ u64 wavekey[2][8];

    const float* base = xyz + (size_t)b * NP * 3;

    float px[16], py[16], pz[16], dist[16];
    {
        const float4* src = reinterpret_cast<const float4*>(base) + t * 12;
        float4 f[12];
        #pragma unroll
        for (int i = 0; i < 12; ++i) f[i] = src[i];
        float fl[48];
        #pragma unroll
        for (int i = 0; i < 12; ++i) {
            fl[4*i] = f[i].x; fl[4*i+1] = f[i].y; fl[4*i+2] = f[i].z; fl[4*i+3] = f[i].w;
        }
        #pragma unroll
        for (int j = 0; j < 16; ++j) {
            px[j] = fl[3*j]; py[j] = fl[3*j+1]; pz[j] = fl[3*j+2];
            dist[j] = 1e10f;
        }
    }

    // first centroid = point 0 (broadcast global load, 16B aligned)
    float cx, cy, cz;
    {
        float4 f0 = *reinterpret_cast<const float4*>(base);
        cx = f0.x; cy = f0.y; cz = f0.z;
        if (t == 0) {
            float* o = out + (size_t)b * NG * 3;
            o[0] = cx; o[1] = cy; o[2] = cz;
        }
    }

    for (int g = 0; g < NG - 1; ++g) {
        float bestd = -1.0f;
        u32 bestj = 0;
        #pragma unroll
        for (int j = 0; j < 16; ++j) {
            float dx = __fsub_rn(px[j], cx);
            float dy = __fsub_rn(py[j], cy);
            float dz = __fsub_rn(pz[j], cz);
            float d  = dist3(dx, dy, dz);
            float dm = fminf(dist[j], d);
            dist[j] = dm;
            bool gt = dm > bestd;              // strict >, ascending j => first max
            bestd = gt ? dm : bestd;
            bestj = gt ? (u32)j : bestj;
        }
        // dm >= 0 so float bits are order-monotone
        u32 hi = __float_as_uint(bestd);
        u32 lo = (u32)(NP - 1 - (t * 16 + (int)bestj));   // larger = smaller idx
        u32 mh = wave_max_u32(hi);
        u32 cl = (hi == mh) ? lo : 0u;
        u32 ml = wave_max_u32(cl);
        if (lane == 0) wavekey[g & 1][wid] = ((u64)mh << 32) | (u64)ml;
        __syncthreads();
        u64 wk = wavekey[g & 1][0];
        #pragma unroll
        for (int w = 1; w < 8; ++w) {
            u64 o = wavekey[g & 1][w];
            wk = (o > wk) ? o : wk;
        }
        const int widx = NP - 1 - (int)(u32)(wk & 0xFFFFFFFFull);
        // broadcast fetch of the new centroid (same address in all lanes; L2-hot)
        const float* cp = base + (size_t)widx * 3;
        cx = cp[0]; cy = cp[1]; cz = cp[2];
        if (t == 0) {
            float* o = out + ((size_t)b * NG + g + 1) * 3;
            o[0] = cx; o[1] = cy; o[2] = cz;
        }
    }
}

// ---------------------------------------------------------------------------
// Kernel 2: 32-NN mean per (batch, center). One WAVE per task. Each lane
// streams 128 points keeping its 4 smallest packed keys; 32 extraction rounds
// now use DPP u64-min (min over dist bits, then min over idx among tied
// lanes) instead of an LDS shuffle butterfly. Exact lazy rescan (filter
// key > last extracted) if a lane's list empties (P ~ 1% per task).
// ---------------------------------------------------------------------------
__device__ __forceinline__ void build_top4(const float4* __restrict__ src,
                                           float cx, float cy, float cz, float s2,
                                           u64 L, bool useL, int lane,
                                           u64& t0, u64& t1, u64& t2, u64& t3)
{
    t0 = t1 = t2 = t3 = ~0ull;
    for (int q = 0; q < 32; ++q) {
        float4 f0 = src[q*3+0];
        float4 f1 = src[q*3+1];
        float4 f2 = src[q*3+2];
        float a[12] = {f0.x,f0.y,f0.z,f0.w, f1.x,f1.y,f1.z,f1.w, f2.x,f2.y,f2.z,f2.w};
        #pragma unroll
        for (int rr = 0; rr < 4; ++rr) {
            float nx = a[rr*3+0], ny = a[rr*3+1], nz = a[rr*3+2];
            // reference: (||s||^2 - 2*(s.n)) + ||n||^2, left-to-right, no FMA
            float dotv = __fadd_rn(__fadd_rn(__fmul_rn(cx,nx), __fmul_rn(cy,ny)), __fmul_rn(cz,nz));
            float n2   = dist3(nx, ny, nz);
            float d    = __fadd_rn(__fsub_rn(s2, __fmul_rn(2.0f, dotv)), n2);
            // monotone map f32 -> u32 (handles the tiny-negative self-distance)
            u32 u  = __float_as_uint(d);
            u32 kk = u ^ (u32)(((int)u >> 31) | 0x80000000);
            int idx = lane * 128 + q * 4 + rr;
            u64 pk = ((u64)kk << 32) | (u64)(u32)idx;
            if (!useL || pk > L) {
                if (pk < t3) {
                    t3 = pk;
                    if (t3 < t2) { u64 tmp = t2; t2 = t3; t3 = tmp; }
                    if (t2 < t1) { u64 tmp = t1; t1 = t2; t2 = tmp; }
                    if (t1 < t0) { u64 tmp = t0; t0 = t1; t1 = tmp; }
                }
            }
        }
    }
}

__global__ __launch_bounds__(256) void knn_kernel(const float* __restrict__ xyz,
                                                  float* __restrict__ out)
{
    const int t    = threadIdx.x;
    const int lane = t & 63;
    const int wid  = t >> 6;
    const int task = blockIdx.x * 4 + wid;   // 0..8191
    const int b    = task >> 8;
    const int g    = task & 255;

    const float* cptr = out + ((size_t)b * NG + g) * 3;   // centers from fps_kernel
    const float cx = cptr[0], cy = cptr[1], cz = cptr[2];
    const float s2 = dist3(cx, cy, cz);

    const float4* src = reinterpret_cast<const float4*>(xyz + (size_t)b * NP * 3) + (size_t)lane * 96;

    u64 t0, t1, t2, t3;
    build_top4(src, cx, cy, cz, s2, 0ull, false, lane, t0, t1, t2, t3);
    int cnt = 4;
    u64 L = 0;
    u32 myWin = 0;

    for (int round = 0; round < NK; ++round) {
        if (cnt == 0) {
            build_top4(src, cx, cy, cz, s2, L, true, lane, t0, t1, t2, t3);
            cnt = 4;
        }
        u32 hi0 = (u32)(t0 >> 32), lo0 = (u32)(t0 & 0xFFFFFFFFull);
        u32 mh = wave_min_u32(hi0);
        u32 cl = (hi0 == mh) ? lo0 : 0xFFFFFFFFu;
        u32 ml = wave_min_u32(cl);              // smaller idx wins ties (matches top_k)
        u64 w  = ((u64)mh << 32) | (u64)ml;
        if (t0 == w) {                          // unique owner (idx packed in key)
            t0 = t1; t1 = t2; t2 = t3; t3 = ~0ull;
            --cnt;
            L = w;
        }
        if (lane == round) myWin = ml;
    }

    float sx = 0.f, sy = 0.f, sz = 0.f;
    if (lane < NK) {
        const float* p = xyz + ((size_t)b * NP + myWin) * 3;
        sx = p[0]; sy = p[1]; sz = p[2];
    }
    #pragma unroll
    for (int m = 32; m >= 1; m >>= 1) {
        sx += __shfl_xor(sx, m, 64);
        sy += __shfl_xor(sy, m, 64);
        sz += __shfl_xor(sz, m, 64);
    }
    if (lane == 0) {
        float* o = out + (size_t)NB * NG * 3 + ((size_t)b * NG + g) * 3;
        const float inv = 1.0f / 32.0f;   // /32 exact (power of 2)
        o[0] = sx * inv; o[1] = sy * inv; o[2] = sz * inv;
    }
}

extern "C" void kernel_launch(void* const* d_in, const int* in_sizes, int n_in,
                              void* d_out, int out_size, void* d_ws, size_t ws_size,
                              hipStream_t stream)
{
    const float* xyz = (const float*)d_in[0];
    float* out = (float*)d_out;

    hipLaunchKernelGGL(fps_kernel, dim3(NB), dim3(512), 0, stream, xyz, out);

    const int tasks  = NB * NG;            // 8192
    const int blocks = tasks / 4;          // 4 waves (tasks) per 256-thread block
    hipLaunchKernelGGL(knn_kernel, dim3(blocks), dim3(256), 0, stream, xyz, out);
}